// Round 12
// baseline (237.726 us; speedup 1.0000x reference)
//
#include <hip/hip_runtime.h>
#include <math.h>

#define SEQL  256
#define HDIM  64
#define PADID 49999
#define NEGV  -4294967295.0f
#define LNEPS 1e-8f
#define INV_SQRT_HS 0.17677669529663687f
#define TKC   257
#define TKTLD 260
#define QG    4
#define ROWS  4096

struct AttnS {
    float Tk[QG][2][TKTLD];
    float A[QG][2][SEQL];
    float Wl[QG][2][TKTLD];
    float outred[4][QG][HDIM];
    float redm[QG][2][4];
    float reds[QG][2][4];
};                                  // 29,184 B
struct WorkSm {
    float xs[4][HDIM];
    float qs[4][HDIM];
    float kx[HDIM][5];
};                                  // 3,328 B
union SmemU { AttnS a; WorkSm w; };

struct FArgs {
    const int *seqs_data, *positions, *tmat;
    const float *apK, *apV, *tVtab, *tKtabT;
    const float *Qo_in, *KpT_in, *Vp_in, *q_in_in;
    const float *g2, *b2, *W1T, *fb1, *W2T, *fb2;        // transposed FFN weights
    const float *g1n, *b1n, *QwT, *Qb, *KwT, *Kb, *VwT, *Vb;  // transposed next-layer
    float *q_in_out, *Qo_out, *KpT_out, *Vp_out;
    const float *lastg, *lastb;
    float *out;
    int final_ln;
};

__device__ __forceinline__ float waveReduceSum(float v) {
#pragma unroll
    for (int o = 32; o > 0; o >>= 1) v += __shfl_xor(v, o);
    return v;
}

// K1: layer-0 LN1 + QKV prep (raw weights staged in LDS) ; blocks 0..4
// transpose tKtab, blocks 5..11 transpose the 7 downstream weight matrices.
__global__ __launch_bounds__(256, 4) void prep_kernel(
    const float* __restrict__ seqs, const int* __restrict__ seqs_data,
    const int* __restrict__ positions,
    const float* __restrict__ Qw, const float* __restrict__ Qb,
    const float* __restrict__ Kw, const float* __restrict__ Kb,
    const float* __restrict__ Vw, const float* __restrict__ Vb,
    const float* __restrict__ g1, const float* __restrict__ b1,
    const float* __restrict__ apK, const float* __restrict__ apV,
    const float* __restrict__ tKtab, const float* __restrict__ W1,
    const float* __restrict__ W2,
    float* __restrict__ tKtabT, float* __restrict__ WT,   // 7 x 4096 block
    float* __restrict__ q_in, float* __restrict__ Qo,
    float* __restrict__ KpT, float* __restrict__ Vp)
{
    __shared__ float t0[64][65];
    __shared__ float t1[64][65];
    __shared__ float xs[4][HDIM];
    __shared__ float qs[4][HDIM];
    __shared__ float kx[HDIM][5];
    const int tid = threadIdx.x;
    const int hw = blockIdx.x;
    const int blk = ((hw & 7) << 7) | (hw >> 3);
    const int w = tid >> 6, t = tid & 63;
    const int row0 = blk << 2;
    const int row = row0 + w;

    if (hw < 5) {           // tKtab slab transpose
        const int s0 = hw * 64;
        const int nrows = (hw == 4) ? (TKC - 256) : 64;
#pragma unroll
        for (int pp = 0; pp < 16; ++pp) {
            int r = pp*4 + w;
            if (r < nrows) t0[r][t] = tKtab[(size_t)(s0 + r)*64 + t];
        }
        __syncthreads();
#pragma unroll
        for (int pp = 0; pp < 16; ++pp) {
            int dd = pp*4 + w;
            if (t < nrows) tKtabT[dd*TKTLD + s0 + t] = t0[t][dd];
        }
        __syncthreads();
    } else if (hw < 12) {   // weight transposes: W1T0,W2T0,QwT1,KwT1,VwT1,W1T1,W2T1
        const int wi = hw - 5;
        const float* src = (wi == 0) ? W1 : (wi == 1) ? W2 :
                           (wi == 2) ? Qw + 4096 : (wi == 3) ? Kw + 4096 :
                           (wi == 4) ? Vw + 4096 : (wi == 5) ? W1 + 4096 : W2 + 4096;
        float* dst = WT + (size_t)wi * 4096;
#pragma unroll
        for (int pp = 0; pp < 16; ++pp)
            t0[pp*4 + w][t] = src[(size_t)(pp*4 + w)*64 + t];
        __syncthreads();
#pragma unroll
        for (int pp = 0; pp < 16; ++pp)
            dst[(size_t)(pp*4 + w)*64 + t] = t0[t][pp*4 + w];
        __syncthreads();
    }

    float x = seqs[(size_t)row * HDIM + t];
    if (seqs_data[row] == PADID) x = 0.f;
    float mean = waveReduceSum(x) * (1.f / HDIM);
    float d = x - mean;
    float var = waveReduceSum(d * d) * (1.f / HDIM);
    float q = g1[t] * d / sqrtf(var + LNEPS) + b1[t];

    xs[w][t] = x;
    qs[w][t] = q;            // same-wave write/read
    q_in[(size_t)row * HDIM + t] = q;

    int pos = positions[row];
    float aK = pos ? apK[(size_t)pos * HDIM + t] : 0.f;
    float aV = pos ? apV[(size_t)pos * HDIM + t] : 0.f;

#pragma unroll
    for (int pp = 0; pp < 16; ++pp) {
        t0[pp*4 + w][t] = Qw[(size_t)(pp*4 + w)*64 + t];
        t1[pp*4 + w][t] = Kw[(size_t)(pp*4 + w)*64 + t];
    }
    __syncthreads();
    float aq = 0.f, ak = 0.f;
#pragma unroll 16
    for (int mth = 0; mth < 64; ++mth) {
        aq += qs[w][mth] * t0[t][mth];     // W[t][m] -> x@W^T
        ak += xs[w][mth] * t1[t][mth];
    }
    Qo[(size_t)row*HDIM + t] = aq + Qb[t];
    kx[t][w] = ak + Kb[t] + aK;
    __syncthreads();
#pragma unroll
    for (int pp = 0; pp < 16; ++pp)
        t0[pp*4 + w][t] = Vw[(size_t)(pp*4 + w)*64 + t];
    KpT[(size_t)(tid>>2)*ROWS + row0 + (tid&3)] = kx[tid>>2][tid&3];
    __syncthreads();
    float av = 0.f;
#pragma unroll 16
    for (int mth = 0; mth < 64; ++mth)
        av += xs[w][mth] * t0[t][mth];
    Vp[(size_t)row*HDIM + t] = av + Vb[t] + aV;
}

// K2/K3: attention (layer L) + LN2/FFN/residual/keep, then next-layer prep
// (final_ln=0) or final LayerNorm (final_ln=1).  Weights read pre-transposed
// from global (coalesced, L2-hot); Q read via wave-uniform global loads.
__global__ __launch_bounds__(256, 5) void attn_ffn_kernel(FArgs p)
{
    __shared__ SmemU sm;
    __shared__ float x2s[QG][HDIM];
    const int tid = threadIdx.x;
    const int hw = blockIdx.x;
    const int blk = ((hw & 7) << 7) | (hw >> 3);
    const int b = blk >> 6, al0 = (blk & 63) << 2;
    const int row0 = blk << 2;
    const int w = tid >> 6, t = tid & 63;
    const int m = tid, lane = t, wv = w;

    // ---------------- attention ----------------
    for (int k = tid; k < QG*2*TKTLD; k += 256) (&sm.a.Wl[0][0][0])[k] = 0.f;
    bool qpad[QG]; bool anypad = false;
#pragma unroll
    for (int li = 0; li < QG; ++li) {
        qpad[li] = (p.seqs_data[row0 + li] == PADID);
        anypad |= qpad[li];
    }
    const int lmax = al0 + QG - 1;
    int tmc[QG];
#pragma unroll
    for (int li = 0; li < QG; ++li)
        tmc[li] = p.tmat[(size_t)(row0 + li)*SEQL + m];

    {   // Tk tile: Q via wave-uniform (scalar) loads, tKtabT coalesced
        const float* q0 = p.Qo_in + (size_t)(row0+0)*HDIM;
        const float* q1 = p.Qo_in + (size_t)(row0+1)*HDIM;
        const float* q2 = p.Qo_in + (size_t)(row0+2)*HDIM;
        const float* q3 = p.Qo_in + (size_t)(row0+3)*HDIM;
        for (int c = tid; c < TKC; c += 256) {
            float a00=0,a10=0,a20=0,a30=0,a01=0,a11=0,a21=0,a31=0;
#pragma unroll 8
            for (int dd = 0; dd < 32; ++dd) {
                float tt = p.tKtabT[dd*TKTLD + c];
                a00 += tt*q0[dd]; a10 += tt*q1[dd];
                a20 += tt*q2[dd]; a30 += tt*q3[dd];
            }
#pragma unroll 8
            for (int dd = 32; dd < 64; ++dd) {
                float tt = p.tKtabT[dd*TKTLD + c];
                a01 += tt*q0[dd]; a11 += tt*q1[dd];
                a21 += tt*q2[dd]; a31 += tt*q3[dd];
            }
            sm.a.Tk[0][0][c]=a00; sm.a.Tk[1][0][c]=a10; sm.a.Tk[2][0][c]=a20; sm.a.Tk[3][0][c]=a30;
            sm.a.Tk[0][1][c]=a01; sm.a.Tk[1][1][c]=a11; sm.a.Tk[2][1][c]=a21; sm.a.Tk[3][1][c]=a31;
        }
    }
    __syncthreads();

    float p0v[QG], p1v[QG];
    const bool waveAllMasked = (wv*64 > lmax) && !anypad;
    if (waveAllMasked) {
#pragma unroll
        for (int li = 0; li < QG; ++li) { p0v[li] = NEGV; p1v[li] = NEGV; }
    } else {
        float s0[QG] = {0,0,0,0}, s1[QG] = {0,0,0,0};
        const float* kpb = p.KpT_in + (size_t)b*SEQL + m;
        const float* qq = p.Qo_in + (size_t)row0*HDIM;   // uniform base
#pragma unroll 8
        for (int dd = 0; dd < 32; ++dd) {
            float kv0 = kpb[(size_t)dd*ROWS];
            float kv1 = kpb[(size_t)(dd+32)*ROWS];
#pragma unroll
            for (int li = 0; li < QG; ++li) {
                s0[li] += kv0 * qq[li*HDIM + dd];
                s1[li] += kv1 * qq[li*HDIM + dd + 32];
            }
        }
#pragma unroll
        for (int li = 0; li < QG; ++li) {
            float v0 = (s0[li] + sm.a.Tk[li][0][tmc[li]]) * INV_SQRT_HS;
            float v1 = (s1[li] + sm.a.Tk[li][1][tmc[li]]) * INV_SQRT_HS;
            bool masked = (m > al0 + li) || qpad[li];
            p0v[li] = masked ? NEGV : v0;
            p1v[li] = masked ? NEGV : v1;
        }
    }
#pragma unroll
    for (int li = 0; li < QG; ++li) {
        float a0 = p0v[li], a1 = p1v[li];
#pragma unroll
        for (int o = 32; o > 0; o >>= 1) {
            a0 = fmaxf(a0, __shfl_xor(a0, o));
            a1 = fmaxf(a1, __shfl_xor(a1, o));
        }
        if (lane == 0) { sm.a.redm[li][0][wv] = a0; sm.a.redm[li][1][wv] = a1; }
    }
    __syncthreads();
#pragma unroll
    for (int li = 0; li < QG; ++li) {
        float m0 = fmaxf(fmaxf(sm.a.redm[li][0][0], sm.a.redm[li][0][1]),
                         fmaxf(sm.a.redm[li][0][2], sm.a.redm[li][0][3]));
        float m1 = fmaxf(fmaxf(sm.a.redm[li][1][0], sm.a.redm[li][1][1]),
                         fmaxf(sm.a.redm[li][1][2], sm.a.redm[li][1][3]));
        float e0 = __expf(p0v[li] - m0), e1 = __expf(p1v[li] - m1);
        p0v[li] = e0; p1v[li] = e1;
        float ts0 = waveReduceSum(e0), ts1 = waveReduceSum(e1);
        if (lane == 0) { sm.a.reds[li][0][wv] = ts0; sm.a.reds[li][1][wv] = ts1; }
    }
    __syncthreads();
#pragma unroll
    for (int li = 0; li < QG; ++li) {
        float sum0 = sm.a.reds[li][0][0]+sm.a.reds[li][0][1]+sm.a.reds[li][0][2]+sm.a.reds[li][0][3];
        float sum1 = sm.a.reds[li][1][0]+sm.a.reds[li][1][1]+sm.a.reds[li][1][2]+sm.a.reds[li][1][3];
        float a0 = p0v[li]/sum0, a1 = p1v[li]/sum1;
        sm.a.A[li][0][m] = a0; sm.a.A[li][1][m] = a1;
        if (a0 != 0.f) atomicAdd(&sm.a.Wl[li][0][tmc[li]], a0);
        if (a1 != 0.f) atomicAdd(&sm.a.Wl[li][1][tmc[li]], a1);
    }
    __syncthreads();

    {   // dense pipelined sweeps
        const int hd = lane, chunk = wv, hh = hd >> 5;
        float acc0=0.f, acc1=0.f, acc2=0.f, acc3=0.f;
        const int mend = anypad ? SEQL : (lmax + 1 < SEQL ? lmax + 1 : SEQL);
        const float* vpb = p.Vp_in + (size_t)(b*SEQL)*HDIM + hd;
        int mm = chunk;
        for (; mm + 12 < mend; mm += 16) {
            float v0 = vpb[(size_t)(mm)    * HDIM];
            float v1 = vpb[(size_t)(mm+4)  * HDIM];
            float v2 = vpb[(size_t)(mm+8)  * HDIM];
            float v3 = vpb[(size_t)(mm+12) * HDIM];
            acc0 += sm.a.A[0][hh][mm]*v0 + sm.a.A[0][hh][mm+4]*v1 + sm.a.A[0][hh][mm+8]*v2 + sm.a.A[0][hh][mm+12]*v3;
            acc1 += sm.a.A[1][hh][mm]*v0 + sm.a.A[1][hh][mm+4]*v1 + sm.a.A[1][hh][mm+8]*v2 + sm.a.A[1][hh][mm+12]*v3;
            acc2 += sm.a.A[2][hh][mm]*v0 + sm.a.A[2][hh][mm+4]*v1 + sm.a.A[2][hh][mm+8]*v2 + sm.a.A[2][hh][mm+12]*v3;
            acc3 += sm.a.A[3][hh][mm]*v0 + sm.a.A[3][hh][mm+4]*v1 + sm.a.A[3][hh][mm+8]*v2 + sm.a.A[3][hh][mm+12]*v3;
        }
        for (; mm < mend; mm += 4) {
            float vp = vpb[(size_t)mm * HDIM];
            acc0 += sm.a.A[0][hh][mm]*vp; acc1 += sm.a.A[1][hh][mm]*vp;
            acc2 += sm.a.A[2][hh][mm]*vp; acc3 += sm.a.A[3][hh][mm]*vp;
        }
        const float* tvb = p.tVtab + hd;
        int c = chunk;
        for (; c + 12 < TKC; c += 16) {
            float t0 = tvb[(size_t)(c)    * HDIM];
            float t1 = tvb[(size_t)(c+4)  * HDIM];
            float t2 = tvb[(size_t)(c+8)  * HDIM];
            float t3 = tvb[(size_t)(c+12) * HDIM];
            acc0 += sm.a.Wl[0][hh][c]*t0 + sm.a.Wl[0][hh][c+4]*t1 + sm.a.Wl[0][hh][c+8]*t2 + sm.a.Wl[0][hh][c+12]*t3;
            acc1 += sm.a.Wl[1][hh][c]*t0 + sm.a.Wl[1][hh][c+4]*t1 + sm.a.Wl[1][hh][c+8]*t2 + sm.a.Wl[1][hh][c+12]*t3;
            acc2 += sm.a.Wl[2][hh][c]*t0 + sm.a.Wl[2][hh][c+4]*t1 + sm.a.Wl[2][hh][c+8]*t2 + sm.a.Wl[2][hh][c+12]*t3;
            acc3 += sm.a.Wl[3][hh][c]*t0 + sm.a.Wl[3][hh][c+4]*t1 + sm.a.Wl[3][hh][c+8]*t2 + sm.a.Wl[3][hh][c+12]*t3;
        }
        for (; c < TKC; c += 4) {
            float tv = tvb[(size_t)c * HDIM];
            acc0 += sm.a.Wl[0][hh][c]*tv; acc1 += sm.a.Wl[1][hh][c]*tv;
            acc2 += sm.a.Wl[2][hh][c]*tv; acc3 += sm.a.Wl[3][hh][c]*tv;
        }
        sm.a.outred[chunk][0][hd] = acc0;
        sm.a.outred[chunk][1][hd] = acc1;
        sm.a.outred[chunk][2][hd] = acc2;
        sm.a.outred[chunk][3][hd] = acc3;
    }
    __syncthreads();
    {
        float o = sm.a.outred[0][w][t] + sm.a.outred[1][w][t]
                + sm.a.outred[2][w][t] + sm.a.outred[3][w][t];
        x2s[w][t] = p.q_in_in[(size_t)(row0 + w)*HDIM + t] + o;
    }
    __syncthreads();   // sm.a reads done; union now reused as sm.w

    // ---------------- LN2 + FFN + residual + keep ----------------
    const int row = row0 + w;
    float xv = x2s[w][t];
    float mean = waveReduceSum(xv) * (1.f/HDIM);
    float d = xv - mean;
    float var = waveReduceSum(d*d) * (1.f/HDIM);
    float s = p.g2[t] * d / sqrtf(var + LNEPS) + p.b2[t];
    sm.w.xs[w][t] = s;                  // wave-local
    float ha = 0.f;
#pragma unroll 16
    for (int mth = 0; mth < 64; ++mth)
        ha += sm.w.xs[w][mth] * p.W1T[(size_t)mth*64 + t];   // coalesced global
    float hv = fmaxf(ha + p.fb1[t], 0.f);
    sm.w.qs[w][t] = hv;                 // wave-local
    float ya = 0.f;
#pragma unroll 16
    for (int mth = 0; mth < 64; ++mth)
        ya += sm.w.qs[w][mth] * p.W2T[(size_t)mth*64 + t];
    float y = ya + p.fb2[t] + s;
    if (p.seqs_data[row] == PADID) y = 0.f;

    if (!p.final_ln) {
        float mean2 = waveReduceSum(y) * (1.f/HDIM);
        float d2 = y - mean2;
        float var2 = waveReduceSum(d2*d2) * (1.f/HDIM);
        float q = p.g1n[t] * d2 / sqrtf(var2 + LNEPS) + p.b1n[t];
        sm.w.xs[w][t] = y;              // wave-local overwrite
        sm.w.qs[w][t] = q;
        p.q_in_out[(size_t)row*HDIM + t] = q;

        int pos = p.positions[row];
        float aK = pos ? p.apK[(size_t)pos*HDIM + t] : 0.f;
        float aV = pos ? p.apV[(size_t)pos*HDIM + t] : 0.f;
        float aq = 0.f, ak = 0.f, av = 0.f;
#pragma unroll 16
        for (int mth = 0; mth < 64; ++mth) {
            float qm = sm.w.qs[w][mth], ym = sm.w.xs[w][mth];
            aq += qm * p.QwT[(size_t)mth*64 + t];
            ak += ym * p.KwT[(size_t)mth*64 + t];
            av += ym * p.VwT[(size_t)mth*64 + t];
        }
        p.Qo_out[(size_t)row*HDIM + t] = aq + p.Qb[t];
        p.Vp_out[(size_t)row*HDIM + t] = av + p.Vb[t] + aV;
        sm.w.kx[t][w] = ak + p.Kb[t] + aK;
        __syncthreads();                // kx is cross-wave
        p.KpT_out[(size_t)(tid>>2)*ROWS + row0 + (tid&3)] = sm.w.kx[tid>>2][tid&3];
    } else {
        float m2 = waveReduceSum(y) * (1.f/HDIM);
        float dd = y - m2;
        float v2 = waveReduceSum(dd*dd) * (1.f/HDIM);
        p.out[(size_t)row*HDIM + t] = p.lastg[t] * dd / sqrtf(v2 + LNEPS) + p.lastb[t];
    }
}

extern "C" void kernel_launch(void* const* d_in, const int* in_sizes, int n_in,
                              void* d_out, int out_size, void* d_ws, size_t ws_size,
                              hipStream_t stream) {
    const int*   seqs_data = (const int*)d_in[0];
    const float* seqs      = (const float*)d_in[1];
    const int*   positions = (const int*)d_in[2];
    const int*   tmat      = (const int*)d_in[3];
    const float* apK       = (const float*)d_in[4];
    const float* apV       = (const float*)d_in[5];
    const float* tKtab     = (const float*)d_in[6];
    const float* tVtab     = (const float*)d_in[7];
    const float* Qw = (const float*)d_in[8];
    const float* Qb = (const float*)d_in[9];
    const float* Kw = (const float*)d_in[10];
    const float* Kb = (const float*)d_in[11];
    const float* Vw = (const float*)d_in[12];
    const float* Vb = (const float*)d_in[13];
    const float* g1 = (const float*)d_in[14];
    const float* b1 = (const float*)d_in[15];
    const float* g2 = (const float*)d_in[16];
    const float* b2 = (const float*)d_in[17];
    const float* W1 = (const float*)d_in[18];
    const float* fb1 = (const float*)d_in[19];
    const float* W2 = (const float*)d_in[20];
    const float* fb2 = (const float*)d_in[21];
    const float* lastg = (const float*)d_in[22];
    const float* lastb = (const float*)d_in[23];

    const size_t N = (size_t)ROWS * HDIM;   // 262144
    float* ws = (float*)d_ws;
    float* q_in0 = ws + 0*N;
    float* q_in1 = ws + 1*N;
    float* Qo0   = ws + 2*N;
    float* Qo1   = ws + 3*N;
    float* Vp0   = ws + 4*N;
    float* Vp1   = ws + 5*N;
    float* KpT0  = ws + 6*N;
    float* KpT1  = ws + 7*N;
    float* tKtabT = ws + 8*N;                  // 64*260
    float* WT    = tKtabT + 64*TKTLD;          // 7 x 4096: W1T0,W2T0,QwT1,KwT1,VwT1,W1T1,W2T1

    prep_kernel<<<1024, 256, 0, stream>>>(
        seqs, seqs_data, positions,
        Qw, Qb, Kw, Kb, Vw, Vb, g1, b1, apK, apV,
        tKtab, W1, W2, tKtabT, WT,
        q_in0, Qo0, KpT0, Vp0);

    FArgs a0;
    a0.seqs_data = seqs_data; a0.positions = positions; a0.tmat = tmat;
    a0.apK = apK; a0.apV = apV; a0.tVtab = tVtab; a0.tKtabT = tKtabT;
    a0.Qo_in = Qo0; a0.KpT_in = KpT0; a0.Vp_in = Vp0; a0.q_in_in = q_in0;
    a0.g2 = g2; a0.b2 = b2;
    a0.W1T = WT + 0*4096; a0.fb1 = fb1;
    a0.W2T = WT + 1*4096; a0.fb2 = fb2;
    a0.g1n = g1 + HDIM; a0.b1n = b1 + HDIM;
    a0.QwT = WT + 2*4096; a0.Qb = Qb + HDIM;
    a0.KwT = WT + 3*4096; a0.Kb = Kb + HDIM;
    a0.VwT = WT + 4*4096; a0.Vb = Vb + HDIM;
    a0.q_in_out = q_in1; a0.Qo_out = Qo1; a0.KpT_out = KpT1; a0.Vp_out = Vp1;
    a0.lastg = lastg; a0.lastb = lastb; a0.out = (float*)d_out;
    a0.final_ln = 0;
    attn_ffn_kernel<<<1024, 256, 0, stream>>>(a0);

    FArgs a1 = a0;
    a1.Qo_in = Qo1; a1.KpT_in = KpT1; a1.Vp_in = Vp1; a1.q_in_in = q_in1;
    a1.g2 = g2 + HDIM; a1.b2 = b2 + HDIM;
    a1.W1T = WT + 5*4096; a1.fb1 = fb1 + HDIM;
    a1.W2T = WT + 6*4096; a1.fb2 = fb2 + HDIM;
    a1.final_ln = 1;
    attn_ffn_kernel<<<1024, 256, 0, stream>>>(a1);
}